// Round 1
// 1839.340 us; speedup vs baseline: 1.3247x; 1.3247x over previous
//
#include <hip/hip_runtime.h>

#define N_NODES 50000
#define N_EDGES 1600000
#define IN_CH   512
#define HID     256
#define OUT_CH  40
#define BN_EPS  1e-5f

typedef __attribute__((ext_vector_type(8))) short s16x8;
typedef __attribute__((ext_vector_type(4))) float f32x4;

__device__ __forceinline__ unsigned short f2bf_rne(float f) {
    unsigned u = __float_as_uint(f);
    u += 0x7FFFu + ((u >> 16) & 1u);
    return (unsigned short)(u >> 16);
}
__device__ __forceinline__ float bf2f(unsigned short s) {
    return __uint_as_float((unsigned)s << 16);
}

// ---------------- degree counting ----------------
__global__ void count_deg_kernel(const int* __restrict__ row, const int* __restrict__ col,
                                 int* __restrict__ deg_row, int* __restrict__ deg_col, int E) {
    int e = blockIdx.x * blockDim.x + threadIdx.x;
    if (e < E) {
        atomicAdd(&deg_row[row[e]], 1);
        atomicAdd(&deg_col[col[e]], 1);
    }
}

__global__ void dis_kernel(const int* __restrict__ deg_row, float* __restrict__ dis, int n) {
    int i = blockIdx.x * blockDim.x + threadIdx.x;
    if (i < n) {
        float d = (float)max(deg_row[i], 1);
        dis[i] = rsqrtf(d);
    }
}

// ---------------- exclusive prefix sum (single block) ----------------
__global__ void scan_kernel(const int* __restrict__ deg, int* __restrict__ offsets, int n) {
    __shared__ int tmp[1024];
    __shared__ int carry_s;
    int tid = threadIdx.x;
    if (tid == 0) { carry_s = 0; offsets[0] = 0; }
    __syncthreads();
    for (int base = 0; base < n; base += 1024) {
        int v = (base + tid < n) ? deg[base + tid] : 0;
        tmp[tid] = v;
        __syncthreads();
        for (int off = 1; off < 1024; off <<= 1) {
            int t = (tid >= off) ? tmp[tid - off] : 0;
            __syncthreads();
            tmp[tid] += t;
            __syncthreads();
        }
        if (base + tid < n) offsets[base + tid + 1] = carry_s + tmp[tid];
        __syncthreads();
        if (tid == 0) carry_s += tmp[1023];
        __syncthreads();
    }
}

// ---------------- CSR fill (group edges by destination col) ----------------
__global__ void fill_csr_kernel(const int* __restrict__ row, const int* __restrict__ col,
                                const float* __restrict__ dis, const int* __restrict__ offsets,
                                int* __restrict__ cursor, int* __restrict__ csr_row,
                                float* __restrict__ csr_norm, int E) {
    int e = blockIdx.x * blockDim.x + threadIdx.x;
    if (e < E) {
        int r = row[e], c = col[e];
        int pos = atomicAdd(&cursor[c], 1);
        int idx = offsets[c] + pos;
        csr_row[idx] = r;
        csr_norm[idx] = dis[r] * dis[c];
    }
}

// ---------------- propagation: out[n] = sum_{e: col=n} norm[e] * hsrc[row[e]] ----------------
__global__ void prop_kernel(const float* __restrict__ hsrc, const int* __restrict__ offsets,
                            const int* __restrict__ csr_row, const float* __restrict__ csr_norm,
                            float* __restrict__ out, int n) {
    int node = blockIdx.x * 4 + (threadIdx.x >> 6);
    int lane = threadIdx.x & 63;
    if (node >= n) return;
    int beg = offsets[node], end = offsets[node + 1];
    float4 acc = make_float4(0.f, 0.f, 0.f, 0.f);
    for (int i = beg; i < end; ++i) {
        int src = csr_row[i];
        float w = csr_norm[i];
        float4 v = ((const float4*)(hsrc + (size_t)src * HID))[lane];
        acc.x += w * v.x; acc.y += w * v.y; acc.z += w * v.z; acc.w += w * v.w;
    }
    ((float4*)(out + (size_t)node * HID))[lane] = acc;
}

// ---------------- tiled transpose: src[R][C] -> dst[C][R] ----------------
__global__ void transpose_kernel(const float* __restrict__ src, float* __restrict__ dst,
                                 int R, int C) {
    __shared__ float tile[32][33];
    int c0 = blockIdx.x * 32, r0 = blockIdx.y * 32;
    int tx = threadIdx.x, ty = threadIdx.y;   // block (32, 8)
    #pragma unroll
    for (int i = 0; i < 32; i += 8) {
        int r = r0 + ty + i, c = c0 + tx;
        tile[ty + i][tx] = (r < R && c < C) ? src[(size_t)r * C + c] : 0.f;
    }
    __syncthreads();
    #pragma unroll
    for (int i = 0; i < 32; i += 8) {
        int c = c0 + ty + i, r = r0 + tx;
        if (c < C && r < R) dst[(size_t)c * R + r] = tile[tx][ty + i];
    }
}

// ---------------- MFMA GEMM: C = act(concat(A0,A1,A2) @ W + b) ----------------
// W supplied pre-transposed: WT[Kout][K]. fp32 emulated via bf16 hi/lo split,
// 3 MFMAs per fragment pair (hi*hi + lo*hi + hi*lo), fp32 accumulate.
#define GBM 128
#define GBN 128
#define GBK 32

__device__ __forceinline__ void split_write(const f32x4& v0, const f32x4& v1,
                                            unsigned short* hi, unsigned short* lo, int idx) {
    s16x8 hv, lv;
    #pragma unroll
    for (int j = 0; j < 8; ++j) {
        float f = (j < 4) ? v0[j] : v1[j - 4];
        unsigned short hs = f2bf_rne(f);
        unsigned short ls = f2bf_rne(f - bf2f(hs));
        hv[j] = (short)hs;
        lv[j] = (short)ls;
    }
    *(s16x8*)&hi[idx] = hv;
    *(s16x8*)&lo[idx] = lv;
}

template<int ACT>  // 0 = none, 1 = relu
__global__ __launch_bounds__(256)
void mfma_gemm_kernel(const float* __restrict__ A0, const float* __restrict__ A1,
                      const float* __restrict__ A2,
                      const float* __restrict__ WT, const float* __restrict__ bvec,
                      float* __restrict__ C,
                      int M, int K, int seg, int Kout) {
    // fragment-friendly LDS: [kgroup(4)][row(128)][8 bf16] -> lane reads contiguous 16B
    __shared__ __attribute__((aligned(16))) unsigned short As_hi[4 * GBM * 8];
    __shared__ __attribute__((aligned(16))) unsigned short As_lo[4 * GBM * 8];
    __shared__ __attribute__((aligned(16))) unsigned short Bs_hi[4 * GBN * 8];
    __shared__ __attribute__((aligned(16))) unsigned short Bs_lo[4 * GBN * 8];

    int tid  = threadIdx.x;
    int lane = tid & 63;
    int w    = tid >> 6;
    int wm   = w & 1, wn = w >> 1;         // 2x2 waves, 64x64 each
    int kg   = lane >> 4, lr = lane & 15;  // fragment lane decomposition
    int bm = blockIdx.x * GBM, bn = blockIdx.y * GBN;

    f32x4 acc[4][4];
    #pragma unroll
    for (int i = 0; i < 4; ++i)
        #pragma unroll
        for (int j = 0; j < 4; ++j)
            acc[i][j] = (f32x4){0.f, 0.f, 0.f, 0.f};

    for (int k0 = 0; k0 < K; k0 += GBK) {
        // segment select (uniform per block per step; seg % 32 == 0 always)
        const float* Ap; int kl0;
        if (k0 < seg)          { Ap = A0; kl0 = k0; }
        else if (k0 < 2 * seg) { Ap = A1; kl0 = k0 - seg; }
        else                   { Ap = A2; kl0 = k0 - 2 * seg; }

        __syncthreads();
        // ---- stage A: 2 (row, kgroup) pairs per thread ----
        #pragma unroll
        for (int q = 0; q < 2; ++q) {
            int p   = tid + q * 256;
            int r_  = p & (GBM - 1);
            int kgq = p >> 7;            // 0..3
            int gm  = bm + r_;
            f32x4 v0 = {0.f, 0.f, 0.f, 0.f}, v1 = {0.f, 0.f, 0.f, 0.f};
            if (gm < M) {
                const float* src = Ap + (size_t)gm * seg + kl0 + kgq * 8;
                v0 = *(const f32x4*)src;
                v1 = *(const f32x4*)(src + 4);
            }
            split_write(v0, v1, As_hi, As_lo, (kgq * GBM + r_) * 8);
        }
        // ---- stage B from WT[Kout][K] ----
        #pragma unroll
        for (int q = 0; q < 2; ++q) {
            int p   = tid + q * 256;
            int r_  = p & (GBN - 1);
            int kgq = p >> 7;
            int gn  = bn + r_;
            f32x4 v0 = {0.f, 0.f, 0.f, 0.f}, v1 = {0.f, 0.f, 0.f, 0.f};
            if (gn < Kout) {
                const float* src = WT + (size_t)gn * K + k0 + kgq * 8;
                v0 = *(const f32x4*)src;
                v1 = *(const f32x4*)(src + 4);
            }
            split_write(v0, v1, Bs_hi, Bs_lo, (kgq * GBN + r_) * 8);
        }
        __syncthreads();

        // ---- fragments + MFMA ----
        s16x8 ah[4], al[4], bh[4], bl[4];
        int abase = (kg * GBM + wm * 64 + lr) * 8;
        int bbase = (kg * GBN + wn * 64 + lr) * 8;
        #pragma unroll
        for (int mf = 0; mf < 4; ++mf) {
            ah[mf] = *(const s16x8*)&As_hi[abase + mf * 16 * 8];
            al[mf] = *(const s16x8*)&As_lo[abase + mf * 16 * 8];
        }
        #pragma unroll
        for (int nf = 0; nf < 4; ++nf) {
            bh[nf] = *(const s16x8*)&Bs_hi[bbase + nf * 16 * 8];
            bl[nf] = *(const s16x8*)&Bs_lo[bbase + nf * 16 * 8];
        }
        #pragma unroll
        for (int mf = 0; mf < 4; ++mf)
            #pragma unroll
            for (int nf = 0; nf < 4; ++nf) {
                acc[mf][nf] = __builtin_amdgcn_mfma_f32_16x16x32_bf16(ah[mf], bh[nf], acc[mf][nf], 0, 0, 0);
                acc[mf][nf] = __builtin_amdgcn_mfma_f32_16x16x32_bf16(al[mf], bh[nf], acc[mf][nf], 0, 0, 0);
                acc[mf][nf] = __builtin_amdgcn_mfma_f32_16x16x32_bf16(ah[mf], bl[nf], acc[mf][nf], 0, 0, 0);
            }
    }

    // ---- epilogue: C/D layout col = lane&15, row = (lane>>4)*4 + reg ----
    #pragma unroll
    for (int nf = 0; nf < 4; ++nf) {
        int col = bn + wn * 64 + nf * 16 + lr;
        if (col >= Kout) continue;
        float bv = bvec[col];
        #pragma unroll
        for (int mf = 0; mf < 4; ++mf) {
            #pragma unroll
            for (int i = 0; i < 4; ++i) {
                int rw = bm + wm * 64 + mf * 16 + kg * 4 + i;
                if (rw < M) {
                    float v = acc[mf][nf][i] + bv;
                    if (ACT == 1) v = fmaxf(v, 0.f);
                    C[(size_t)rw * Kout + col] = v;
                }
            }
        }
    }
}

// ---------------- BN column stats ----------------
__global__ void colstats_kernel(const float* __restrict__ y, float* __restrict__ sums,
                                float* __restrict__ sumsq, int M) {
    int col = threadIdx.x;  // 256 threads = HID
    int r0 = blockIdx.x * 128;
    int r1 = min(r0 + 128, M);
    float s = 0.f, s2 = 0.f;
    for (int r = r0; r < r1; ++r) {
        float v = y[(size_t)r * HID + col];
        s += v; s2 += v * v;
    }
    atomicAdd(&sums[col], s);
    atomicAdd(&sumsq[col], s2);
}

__global__ void bnrelu_kernel(const float* __restrict__ y, const float* __restrict__ sums,
                              const float* __restrict__ sumsq, const float* __restrict__ g,
                              const float* __restrict__ beta, float* __restrict__ h, int M) {
    int idx = blockIdx.x * blockDim.x + threadIdx.x;
    if (idx < M * HID) {
        int col = idx & (HID - 1);
        float invM = 1.0f / (float)M;
        float mean = sums[col] * invM;
        float var  = fmaxf(sumsq[col] * invM - mean * mean, 0.f);
        float v = (y[idx] - mean) * rsqrtf(var + BN_EPS) * g[col] + beta[col];
        h[idx] = fmaxf(v, 0.f);
    }
}

extern "C" void kernel_launch(void* const* d_in, const int* in_sizes, int n_in,
                              void* d_out, int out_size, void* d_ws, size_t ws_size,
                              hipStream_t stream) {
    const float* x      = (const float*)d_in[0];
    const int*   ei     = (const int*)d_in[1];
    const float* W_feat = (const float*)d_in[2];
    const float* b_feat = (const float*)d_in[3];
    const float* W0     = (const float*)d_in[4];
    const float* b0     = (const float*)d_in[5];
    const float* g0     = (const float*)d_in[6];
    const float* beta0  = (const float*)d_in[7];
    const float* W1     = (const float*)d_in[8];
    const float* b1     = (const float*)d_in[9];
    const float* g1     = (const float*)d_in[10];
    const float* beta1  = (const float*)d_in[11];
    const float* Wc     = (const float*)d_in[12];
    const float* bc     = (const float*)d_in[13];
    float* out = (float*)d_out;

    const int N = N_NODES, E = N_EDGES;
    const int* row = ei;
    const int* col = ei + E;

    // workspace carve-up
    char* ws = (char*)d_ws;
    size_t off = 0;
    auto alloc = [&](size_t bytes) -> void* {
        void* p = ws + off;
        off = (off + bytes + 255) & ~(size_t)255;
        return p;
    };
    int*   deg_row  = (int*)  alloc(N * 4);
    int*   deg_col  = (int*)  alloc(N * 4);
    int*   cursor   = (int*)  alloc(N * 4);
    int*   offsets  = (int*)  alloc((N + 1) * 4);
    float* dis      = (float*)alloc(N * 4);
    int*   csr_row  = (int*)  alloc((size_t)E * 4);
    float* csr_norm = (float*)alloc((size_t)E * 4);
    float* h        = (float*)alloc((size_t)N * HID * 4);
    float* agg1     = (float*)alloc((size_t)N * HID * 4);
    float* agg2     = (float*)alloc((size_t)N * HID * 4);
    float* y        = (float*)alloc((size_t)N * HID * 4);
    float* sums     = (float*)alloc(HID * 4);
    float* sumsq    = (float*)alloc(HID * 4);
    float* WTf      = (float*)alloc((size_t)HID * IN_CH * 4);      // 256 x 512
    float* WT0     = (float*)alloc((size_t)HID * 3 * HID * 4);     // 256 x 768
    float* WT1     = (float*)alloc((size_t)HID * 3 * HID * 4);     // 256 x 768
    float* WTc     = (float*)alloc((size_t)OUT_CH * HID * 4);      // 40 x 256

    hipMemsetAsync(deg_row, 0, N * 4, stream);
    hipMemsetAsync(deg_col, 0, N * 4, stream);
    hipMemsetAsync(cursor, 0, N * 4, stream);

    // weight transposes (independent of CSR build)
    dim3 tb(32, 8);
    transpose_kernel<<<dim3((HID + 31) / 32, (IN_CH + 31) / 32), tb, 0, stream>>>(W_feat, WTf, IN_CH, HID);
    transpose_kernel<<<dim3((HID + 31) / 32, (3 * HID + 31) / 32), tb, 0, stream>>>(W0, WT0, 3 * HID, HID);
    transpose_kernel<<<dim3((HID + 31) / 32, (3 * HID + 31) / 32), tb, 0, stream>>>(W1, WT1, 3 * HID, HID);
    transpose_kernel<<<dim3((OUT_CH + 31) / 32, (HID + 31) / 32), tb, 0, stream>>>(Wc, WTc, HID, OUT_CH);

    count_deg_kernel<<<(E + 255) / 256, 256, 0, stream>>>(row, col, deg_row, deg_col, E);
    dis_kernel<<<(N + 255) / 256, 256, 0, stream>>>(deg_row, dis, N);
    scan_kernel<<<1, 1024, 0, stream>>>(deg_col, offsets, N);
    fill_csr_kernel<<<(E + 255) / 256, 256, 0, stream>>>(row, col, dis, offsets, cursor,
                                                         csr_row, csr_norm, E);

    dim3 gemm_grid((N + GBM - 1) / GBM, (HID + GBN - 1) / GBN);
    // h = relu(x @ W_feat + b_feat)
    mfma_gemm_kernel<1><<<gemm_grid, 256, 0, stream>>>(x, nullptr, nullptr, WTf, b_feat, h,
                                                       N, IN_CH, IN_CH, HID);

    const float* WTs[2]   = {WT0, WT1};
    const float* bs[2]    = {b0, b1};
    const float* gs[2]    = {g0, g1};
    const float* betas[2] = {beta0, beta1};
    int prop_grid = (N + 3) / 4;
    for (int layer = 0; layer < 2; ++layer) {
        prop_kernel<<<prop_grid, 256, 0, stream>>>(h, offsets, csr_row, csr_norm, agg1, N);
        prop_kernel<<<prop_grid, 256, 0, stream>>>(agg1, offsets, csr_row, csr_norm, agg2, N);
        mfma_gemm_kernel<0><<<gemm_grid, 256, 0, stream>>>(h, agg1, agg2, WTs[layer], bs[layer], y,
                                                           N, 3 * HID, HID, HID);
        hipMemsetAsync(sums, 0, HID * 4, stream);
        hipMemsetAsync(sumsq, 0, HID * 4, stream);
        colstats_kernel<<<(N + 127) / 128, HID, 0, stream>>>(y, sums, sumsq, N);
        bnrelu_kernel<<<(N * HID + 255) / 256, 256, 0, stream>>>(y, sums, sumsq, gs[layer],
                                                                 betas[layer], h, N);
    }

    dim3 out_grid((N + GBM - 1) / GBM, (OUT_CH + GBN - 1) / GBN);
    mfma_gemm_kernel<0><<<out_grid, 256, 0, stream>>>(h, nullptr, nullptr, WTc, bc, out,
                                                      N, HID, HID, OUT_CH);
}

// Round 2
// 1456.277 us; speedup vs baseline: 1.6731x; 1.2630x over previous
//
#include <hip/hip_runtime.h>

#define N_NODES 50000
#define N_EDGES 1600000
#define IN_CH   512
#define HID     256
#define OUT_CH  40
#define BN_EPS  1e-5f

typedef __attribute__((ext_vector_type(8))) short s16x8;
typedef __attribute__((ext_vector_type(4))) float f32x4;

__device__ __forceinline__ unsigned short f2bf_rne(float f) {
    unsigned u = __float_as_uint(f);
    u += 0x7FFFu + ((u >> 16) & 1u);
    return (unsigned short)(u >> 16);
}
__device__ __forceinline__ float bf2f(unsigned short s) {
    return __uint_as_float((unsigned)s << 16);
}

// ---------------- degree counting ----------------
__global__ void count_deg_kernel(const int* __restrict__ row, const int* __restrict__ col,
                                 int* __restrict__ deg_row, int* __restrict__ deg_col, int E) {
    int e = blockIdx.x * blockDim.x + threadIdx.x;
    if (e < E) {
        atomicAdd(&deg_row[row[e]], 1);
        atomicAdd(&deg_col[col[e]], 1);
    }
}

__global__ void dis_kernel(const int* __restrict__ deg_row, float* __restrict__ dis, int n) {
    int i = blockIdx.x * blockDim.x + threadIdx.x;
    if (i < n) {
        float d = (float)max(deg_row[i], 1);
        dis[i] = rsqrtf(d);
    }
}

// ---------------- exclusive prefix sum (single block) ----------------
__global__ void scan_kernel(const int* __restrict__ deg, int* __restrict__ offsets, int n) {
    __shared__ int tmp[1024];
    __shared__ int carry_s;
    int tid = threadIdx.x;
    if (tid == 0) { carry_s = 0; offsets[0] = 0; }
    __syncthreads();
    for (int base = 0; base < n; base += 1024) {
        int v = (base + tid < n) ? deg[base + tid] : 0;
        tmp[tid] = v;
        __syncthreads();
        for (int off = 1; off < 1024; off <<= 1) {
            int t = (tid >= off) ? tmp[tid - off] : 0;
            __syncthreads();
            tmp[tid] += t;
            __syncthreads();
        }
        if (base + tid < n) offsets[base + tid + 1] = carry_s + tmp[tid];
        __syncthreads();
        if (tid == 0) carry_s += tmp[1023];
        __syncthreads();
    }
}

// ---------------- CSR fill (group edges by destination col) ----------------
__global__ void fill_csr_kernel(const int* __restrict__ row, const int* __restrict__ col,
                                const float* __restrict__ dis, const int* __restrict__ offsets,
                                int* __restrict__ cursor, int* __restrict__ csr_row,
                                float* __restrict__ csr_norm, int E) {
    int e = blockIdx.x * blockDim.x + threadIdx.x;
    if (e < E) {
        int r = row[e], c = col[e];
        int pos = atomicAdd(&cursor[c], 1);
        int idx = offsets[c] + pos;
        csr_row[idx] = r;
        csr_norm[idx] = dis[r] * dis[c];
    }
}

// ---------------- propagation: out[n] = sum_{e: col=n} norm[e] * hsrc[row[e]] ----------------
// gathers bf16 rows (512B/row), accumulates fp32, writes fp32 (+ optional bf16 shadow)
template<int WRITE_BF>
__global__ void prop_kernel(const unsigned short* __restrict__ hsrc,
                            const int* __restrict__ offsets,
                            const int* __restrict__ csr_row, const float* __restrict__ csr_norm,
                            float* __restrict__ out, unsigned short* __restrict__ out_bf, int n) {
    int node = blockIdx.x * 4 + (threadIdx.x >> 6);
    int lane = threadIdx.x & 63;
    if (node >= n) return;
    int beg = offsets[node], end = offsets[node + 1];
    float4 acc = make_float4(0.f, 0.f, 0.f, 0.f);
    int i = beg;
    for (; i + 2 <= end; i += 2) {
        int s0 = csr_row[i], s1 = csr_row[i + 1];
        float w0 = csr_norm[i], w1 = csr_norm[i + 1];
        ushort4 v0 = ((const ushort4*)(hsrc + (size_t)s0 * HID))[lane];
        ushort4 v1 = ((const ushort4*)(hsrc + (size_t)s1 * HID))[lane];
        acc.x += w0 * bf2f(v0.x); acc.y += w0 * bf2f(v0.y);
        acc.z += w0 * bf2f(v0.z); acc.w += w0 * bf2f(v0.w);
        acc.x += w1 * bf2f(v1.x); acc.y += w1 * bf2f(v1.y);
        acc.z += w1 * bf2f(v1.z); acc.w += w1 * bf2f(v1.w);
    }
    if (i < end) {
        int s0 = csr_row[i];
        float w0 = csr_norm[i];
        ushort4 v0 = ((const ushort4*)(hsrc + (size_t)s0 * HID))[lane];
        acc.x += w0 * bf2f(v0.x); acc.y += w0 * bf2f(v0.y);
        acc.z += w0 * bf2f(v0.z); acc.w += w0 * bf2f(v0.w);
    }
    ((float4*)(out + (size_t)node * HID))[lane] = acc;
    if (WRITE_BF) {
        ushort4 ob;
        ob.x = f2bf_rne(acc.x); ob.y = f2bf_rne(acc.y);
        ob.z = f2bf_rne(acc.z); ob.w = f2bf_rne(acc.w);
        ((ushort4*)(out_bf + (size_t)node * HID))[lane] = ob;
    }
}

// ---------------- tiled transpose: src[R][C] -> dst[C][R] ----------------
__global__ void transpose_kernel(const float* __restrict__ src, float* __restrict__ dst,
                                 int R, int C) {
    __shared__ float tile[32][33];
    int c0 = blockIdx.x * 32, r0 = blockIdx.y * 32;
    int tx = threadIdx.x, ty = threadIdx.y;   // block (32, 8)
    #pragma unroll
    for (int i = 0; i < 32; i += 8) {
        int r = r0 + ty + i, c = c0 + tx;
        tile[ty + i][tx] = (r < R && c < C) ? src[(size_t)r * C + c] : 0.f;
    }
    __syncthreads();
    #pragma unroll
    for (int i = 0; i < 32; i += 8) {
        int c = c0 + ty + i, r = r0 + tx;
        if (c < C && r < R) dst[(size_t)c * R + r] = tile[tx][ty + i];
    }
}

// ---------------- MFMA GEMM: C = act(concat(A0,A1,A2) @ W + b) ----------------
// W supplied pre-transposed: WT[Kout][K]. fp32 emulated via bf16 hi/lo split,
// 3 MFMAs per fragment pair (hi*hi + lo*hi + hi*lo), fp32 accumulate.
#define GBM 128
#define GBN 128
#define GBK 32

__device__ __forceinline__ void split_write(const f32x4& v0, const f32x4& v1,
                                            unsigned short* hi, unsigned short* lo, int idx) {
    s16x8 hv, lv;
    #pragma unroll
    for (int j = 0; j < 8; ++j) {
        float f = (j < 4) ? v0[j] : v1[j - 4];
        unsigned short hs = f2bf_rne(f);
        unsigned short ls = f2bf_rne(f - bf2f(hs));
        hv[j] = (short)hs;
        lv[j] = (short)ls;
    }
    *(s16x8*)&hi[idx] = hv;
    *(s16x8*)&lo[idx] = lv;
}

template<int ACT, int WBF>  // ACT: 0 = none, 1 = relu; WBF: also write bf16 shadow
__global__ __launch_bounds__(256)
void mfma_gemm_kernel(const float* __restrict__ A0, const float* __restrict__ A1,
                      const float* __restrict__ A2,
                      const float* __restrict__ WT, const float* __restrict__ bvec,
                      float* __restrict__ C, unsigned short* __restrict__ Cbf,
                      int M, int K, int seg, int Kout) {
    // fragment-friendly LDS: [kgroup(4)][row(128)][8 bf16] -> lane reads contiguous 16B
    __shared__ __attribute__((aligned(16))) unsigned short As_hi[4 * GBM * 8];
    __shared__ __attribute__((aligned(16))) unsigned short As_lo[4 * GBM * 8];
    __shared__ __attribute__((aligned(16))) unsigned short Bs_hi[4 * GBN * 8];
    __shared__ __attribute__((aligned(16))) unsigned short Bs_lo[4 * GBN * 8];

    int tid  = threadIdx.x;
    int lane = tid & 63;
    int w    = tid >> 6;
    int wm   = w & 1, wn = w >> 1;         // 2x2 waves, 64x64 each
    int kg   = lane >> 4, lr = lane & 15;  // fragment lane decomposition
    int bm = blockIdx.x * GBM, bn = blockIdx.y * GBN;

    f32x4 acc[4][4];
    #pragma unroll
    for (int i = 0; i < 4; ++i)
        #pragma unroll
        for (int j = 0; j < 4; ++j)
            acc[i][j] = (f32x4){0.f, 0.f, 0.f, 0.f};

    for (int k0 = 0; k0 < K; k0 += GBK) {
        // segment select (uniform per block per step; seg % 32 == 0 always)
        const float* Ap; int kl0;
        if (k0 < seg)          { Ap = A0; kl0 = k0; }
        else if (k0 < 2 * seg) { Ap = A1; kl0 = k0 - seg; }
        else                   { Ap = A2; kl0 = k0 - 2 * seg; }

        __syncthreads();
        // ---- stage A: 2 (row, kgroup) pairs per thread ----
        #pragma unroll
        for (int q = 0; q < 2; ++q) {
            int p   = tid + q * 256;
            int r_  = p & (GBM - 1);
            int kgq = p >> 7;            // 0..3
            int gm  = bm + r_;
            f32x4 v0 = {0.f, 0.f, 0.f, 0.f}, v1 = {0.f, 0.f, 0.f, 0.f};
            if (gm < M) {
                const float* src = Ap + (size_t)gm * seg + kl0 + kgq * 8;
                v0 = *(const f32x4*)src;
                v1 = *(const f32x4*)(src + 4);
            }
            split_write(v0, v1, As_hi, As_lo, (kgq * GBM + r_) * 8);
        }
        // ---- stage B from WT[Kout][K] ----
        #pragma unroll
        for (int q = 0; q < 2; ++q) {
            int p   = tid + q * 256;
            int r_  = p & (GBN - 1);
            int kgq = p >> 7;
            int gn  = bn + r_;
            f32x4 v0 = {0.f, 0.f, 0.f, 0.f}, v1 = {0.f, 0.f, 0.f, 0.f};
            if (gn < Kout) {
                const float* src = WT + (size_t)gn * K + k0 + kgq * 8;
                v0 = *(const f32x4*)src;
                v1 = *(const f32x4*)(src + 4);
            }
            split_write(v0, v1, Bs_hi, Bs_lo, (kgq * GBN + r_) * 8);
        }
        __syncthreads();

        // ---- fragments + MFMA ----
        s16x8 ah[4], al[4], bh[4], bl[4];
        int abase = (kg * GBM + wm * 64 + lr) * 8;
        int bbase = (kg * GBN + wn * 64 + lr) * 8;
        #pragma unroll
        for (int mf = 0; mf < 4; ++mf) {
            ah[mf] = *(const s16x8*)&As_hi[abase + mf * 16 * 8];
            al[mf] = *(const s16x8*)&As_lo[abase + mf * 16 * 8];
        }
        #pragma unroll
        for (int nf = 0; nf < 4; ++nf) {
            bh[nf] = *(const s16x8*)&Bs_hi[bbase + nf * 16 * 8];
            bl[nf] = *(const s16x8*)&Bs_lo[bbase + nf * 16 * 8];
        }
        #pragma unroll
        for (int mf = 0; mf < 4; ++mf)
            #pragma unroll
            for (int nf = 0; nf < 4; ++nf) {
                acc[mf][nf] = __builtin_amdgcn_mfma_f32_16x16x32_bf16(ah[mf], bh[nf], acc[mf][nf], 0, 0, 0);
                acc[mf][nf] = __builtin_amdgcn_mfma_f32_16x16x32_bf16(al[mf], bh[nf], acc[mf][nf], 0, 0, 0);
                acc[mf][nf] = __builtin_amdgcn_mfma_f32_16x16x32_bf16(ah[mf], bl[nf], acc[mf][nf], 0, 0, 0);
            }
    }

    // ---- epilogue: C/D layout col = lane&15, row = (lane>>4)*4 + reg ----
    #pragma unroll
    for (int nf = 0; nf < 4; ++nf) {
        int col = bn + wn * 64 + nf * 16 + lr;
        if (col >= Kout) continue;
        float bv = bvec[col];
        #pragma unroll
        for (int mf = 0; mf < 4; ++mf) {
            #pragma unroll
            for (int i = 0; i < 4; ++i) {
                int rw = bm + wm * 64 + mf * 16 + kg * 4 + i;
                if (rw < M) {
                    float v = acc[mf][nf][i] + bv;
                    if (ACT == 1) v = fmaxf(v, 0.f);
                    C[(size_t)rw * Kout + col] = v;
                    if (WBF) Cbf[(size_t)rw * Kout + col] = f2bf_rne(v);
                }
            }
        }
    }
}

// ---------------- BN column stats ----------------
__global__ void colstats_kernel(const float* __restrict__ y, float* __restrict__ sums,
                                float* __restrict__ sumsq, int M) {
    int col = threadIdx.x;  // 256 threads = HID
    int r0 = blockIdx.x * 128;
    int r1 = min(r0 + 128, M);
    float s = 0.f, s2 = 0.f;
    for (int r = r0; r < r1; ++r) {
        float v = y[(size_t)r * HID + col];
        s += v; s2 += v * v;
    }
    atomicAdd(&sums[col], s);
    atomicAdd(&sumsq[col], s2);
}

__global__ void bnrelu_kernel(const float* __restrict__ y, const float* __restrict__ sums,
                              const float* __restrict__ sumsq, const float* __restrict__ g,
                              const float* __restrict__ beta, float* __restrict__ h,
                              unsigned short* __restrict__ h_bf, int M) {
    int idx = blockIdx.x * blockDim.x + threadIdx.x;   // group of 4 channels
    if (idx < M * HID / 4) {
        int col0 = (idx * 4) & (HID - 1);
        float4 v = ((const float4*)y)[idx];
        float invM = 1.0f / (float)M;
        float r[4] = {v.x, v.y, v.z, v.w};
        ushort4 ob;
        unsigned short* obp = (unsigned short*)&ob;
        #pragma unroll
        for (int j = 0; j < 4; ++j) {
            int col = col0 + j;
            float mean = sums[col] * invM;
            float var  = fmaxf(sumsq[col] * invM - mean * mean, 0.f);
            float o = (r[j] - mean) * rsqrtf(var + BN_EPS) * g[col] + beta[col];
            o = fmaxf(o, 0.f);
            r[j] = o;
            obp[j] = f2bf_rne(o);
        }
        ((float4*)h)[idx] = make_float4(r[0], r[1], r[2], r[3]);
        ((ushort4*)h_bf)[idx] = ob;
    }
}

extern "C" void kernel_launch(void* const* d_in, const int* in_sizes, int n_in,
                              void* d_out, int out_size, void* d_ws, size_t ws_size,
                              hipStream_t stream) {
    const float* x      = (const float*)d_in[0];
    const int*   ei     = (const int*)d_in[1];
    const float* W_feat = (const float*)d_in[2];
    const float* b_feat = (const float*)d_in[3];
    const float* W0     = (const float*)d_in[4];
    const float* b0     = (const float*)d_in[5];
    const float* g0     = (const float*)d_in[6];
    const float* beta0  = (const float*)d_in[7];
    const float* W1     = (const float*)d_in[8];
    const float* b1     = (const float*)d_in[9];
    const float* g1     = (const float*)d_in[10];
    const float* beta1  = (const float*)d_in[11];
    const float* Wc     = (const float*)d_in[12];
    const float* bc     = (const float*)d_in[13];
    float* out = (float*)d_out;

    const int N = N_NODES, E = N_EDGES;
    const int* row = ei;
    const int* col = ei + E;

    // workspace carve-up
    char* ws = (char*)d_ws;
    size_t off = 0;
    auto alloc = [&](size_t bytes) -> void* {
        void* p = ws + off;
        off = (off + bytes + 255) & ~(size_t)255;
        return p;
    };
    int*   deg_row  = (int*)  alloc(N * 4);
    int*   deg_col  = (int*)  alloc(N * 4);
    int*   cursor   = (int*)  alloc(N * 4);
    int*   offsets  = (int*)  alloc((N + 1) * 4);
    float* dis      = (float*)alloc(N * 4);
    int*   csr_row  = (int*)  alloc((size_t)E * 4);
    float* csr_norm = (float*)alloc((size_t)E * 4);
    float* h        = (float*)alloc((size_t)N * HID * 4);
    float* agg1     = (float*)alloc((size_t)N * HID * 4);
    float* agg2     = (float*)alloc((size_t)N * HID * 4);
    float* y        = (float*)alloc((size_t)N * HID * 4);
    unsigned short* h_bf    = (unsigned short*)alloc((size_t)N * HID * 2);
    unsigned short* agg1_bf = (unsigned short*)alloc((size_t)N * HID * 2);
    float* sums     = (float*)alloc(HID * 4);
    float* sumsq    = (float*)alloc(HID * 4);
    float* WTf      = (float*)alloc((size_t)HID * IN_CH * 4);      // 256 x 512
    float* WT0     = (float*)alloc((size_t)HID * 3 * HID * 4);     // 256 x 768
    float* WT1     = (float*)alloc((size_t)HID * 3 * HID * 4);     // 256 x 768
    float* WTc     = (float*)alloc((size_t)OUT_CH * HID * 4);      // 40 x 256

    hipMemsetAsync(deg_row, 0, N * 4, stream);
    hipMemsetAsync(deg_col, 0, N * 4, stream);
    hipMemsetAsync(cursor, 0, N * 4, stream);

    // weight transposes (independent of CSR build)
    dim3 tb(32, 8);
    transpose_kernel<<<dim3((HID + 31) / 32, (IN_CH + 31) / 32), tb, 0, stream>>>(W_feat, WTf, IN_CH, HID);
    transpose_kernel<<<dim3((HID + 31) / 32, (3 * HID + 31) / 32), tb, 0, stream>>>(W0, WT0, 3 * HID, HID);
    transpose_kernel<<<dim3((HID + 31) / 32, (3 * HID + 31) / 32), tb, 0, stream>>>(W1, WT1, 3 * HID, HID);
    transpose_kernel<<<dim3((OUT_CH + 31) / 32, (HID + 31) / 32), tb, 0, stream>>>(Wc, WTc, HID, OUT_CH);

    count_deg_kernel<<<(E + 255) / 256, 256, 0, stream>>>(row, col, deg_row, deg_col, E);
    dis_kernel<<<(N + 255) / 256, 256, 0, stream>>>(deg_row, dis, N);
    scan_kernel<<<1, 1024, 0, stream>>>(deg_col, offsets, N);
    fill_csr_kernel<<<(E + 255) / 256, 256, 0, stream>>>(row, col, dis, offsets, cursor,
                                                         csr_row, csr_norm, E);

    dim3 gemm_grid((N + GBM - 1) / GBM, (HID + GBN - 1) / GBN);
    // h = relu(x @ W_feat + b_feat), plus bf16 shadow for prop gather
    mfma_gemm_kernel<1, 1><<<gemm_grid, 256, 0, stream>>>(x, nullptr, nullptr, WTf, b_feat, h,
                                                          h_bf, N, IN_CH, IN_CH, HID);

    const float* WTs[2]   = {WT0, WT1};
    const float* bs[2]    = {b0, b1};
    const float* gs[2]    = {g0, g1};
    const float* betas[2] = {beta0, beta1};
    int prop_grid = (N + 3) / 4;
    for (int layer = 0; layer < 2; ++layer) {
        prop_kernel<1><<<prop_grid, 256, 0, stream>>>(h_bf, offsets, csr_row, csr_norm,
                                                      agg1, agg1_bf, N);
        prop_kernel<0><<<prop_grid, 256, 0, stream>>>(agg1_bf, offsets, csr_row, csr_norm,
                                                      agg2, nullptr, N);
        mfma_gemm_kernel<0, 0><<<gemm_grid, 256, 0, stream>>>(h, agg1, agg2, WTs[layer], bs[layer],
                                                              y, nullptr, N, 3 * HID, HID, HID);
        hipMemsetAsync(sums, 0, HID * 4, stream);
        hipMemsetAsync(sumsq, 0, HID * 4, stream);
        colstats_kernel<<<(N + 127) / 128, HID, 0, stream>>>(y, sums, sumsq, N);
        bnrelu_kernel<<<(N * HID / 4 + 255) / 256, 256, 0, stream>>>(y, sums, sumsq, gs[layer],
                                                                     betas[layer], h, h_bf, N);
    }

    dim3 out_grid((N + GBM - 1) / GBM, (OUT_CH + GBN - 1) / GBN);
    mfma_gemm_kernel<0, 0><<<out_grid, 256, 0, stream>>>(h, nullptr, nullptr, WTc, bc, out,
                                                         nullptr, N, HID, HID, OUT_CH);
}

// Round 3
// 1322.491 us; speedup vs baseline: 1.8424x; 1.1012x over previous
//
#include <hip/hip_runtime.h>

#define N_NODES 50000
#define N_PAD   50048
#define N_EDGES 1600000
#define IN_CH   512
#define HID     256
#define OUT_CH  40
#define BN_EPS  1e-5f

typedef __attribute__((ext_vector_type(8))) short s16x8;
typedef __attribute__((ext_vector_type(4))) float f32x4;

__device__ __forceinline__ unsigned short f2bf_rne(float f) {
    unsigned u = __float_as_uint(f);
    u += 0x7FFFu + ((u >> 16) & 1u);
    return (unsigned short)(u >> 16);
}
__device__ __forceinline__ float bf2f(unsigned short s) {
    return __uint_as_float((unsigned)s << 16);
}

// async global->LDS, 16B per lane; LDS dest is wave-uniform base + lane*16
__device__ __forceinline__ void gload_lds16(const void* gsrc, void* ldst) {
    __builtin_amdgcn_global_load_lds(
        (const __attribute__((address_space(1))) unsigned int*)gsrc,
        (__attribute__((address_space(3))) unsigned int*)ldst,
        16, 0, 0);
}

// ---------------- degree counting ----------------
__global__ void count_deg_kernel(const int* __restrict__ row, const int* __restrict__ col,
                                 int* __restrict__ deg_row, int* __restrict__ deg_col, int E) {
    int e = blockIdx.x * blockDim.x + threadIdx.x;
    if (e < E) {
        atomicAdd(&deg_row[row[e]], 1);
        atomicAdd(&deg_col[col[e]], 1);
    }
}

__global__ void dis_kernel(const int* __restrict__ deg_row, float* __restrict__ dis, int n) {
    int i = blockIdx.x * blockDim.x + threadIdx.x;
    if (i < n) {
        float d = (float)max(deg_row[i], 1);
        dis[i] = rsqrtf(d);
    }
}

// ---------------- exclusive prefix sum (single block) ----------------
__global__ void scan_kernel(const int* __restrict__ deg, int* __restrict__ offsets, int n) {
    __shared__ int tmp[1024];
    __shared__ int carry_s;
    int tid = threadIdx.x;
    if (tid == 0) { carry_s = 0; offsets[0] = 0; }
    __syncthreads();
    for (int base = 0; base < n; base += 1024) {
        int v = (base + tid < n) ? deg[base + tid] : 0;
        tmp[tid] = v;
        __syncthreads();
        for (int off = 1; off < 1024; off <<= 1) {
            int t = (tid >= off) ? tmp[tid - off] : 0;
            __syncthreads();
            tmp[tid] += t;
            __syncthreads();
        }
        if (base + tid < n) offsets[base + tid + 1] = carry_s + tmp[tid];
        __syncthreads();
        if (tid == 0) carry_s += tmp[1023];
        __syncthreads();
    }
}

// ---------------- CSR fill (group edges by destination col) ----------------
__global__ void fill_csr_kernel(const int* __restrict__ row, const int* __restrict__ col,
                                const float* __restrict__ dis, const int* __restrict__ offsets,
                                int* __restrict__ cursor, int* __restrict__ csr_row,
                                float* __restrict__ csr_norm, int E) {
    int e = blockIdx.x * blockDim.x + threadIdx.x;
    if (e < E) {
        int r = row[e], c = col[e];
        int pos = atomicAdd(&cursor[c], 1);
        int idx = offsets[c] + pos;
        csr_row[idx] = r;
        csr_norm[idx] = dis[r] * dis[c];
    }
}

// ---------------- x hi/lo split ----------------
__global__ void split_x_kernel(const float* __restrict__ x, unsigned short* __restrict__ xhi,
                               unsigned short* __restrict__ xlo, int n4) {
    int i = blockIdx.x * blockDim.x + threadIdx.x;
    if (i < n4) {
        float4 v = ((const float4*)x)[i];
        float r[4] = {v.x, v.y, v.z, v.w};
        ushort4 hs, ls;
        unsigned short* hp = (unsigned short*)&hs;
        unsigned short* lp = (unsigned short*)&ls;
        #pragma unroll
        for (int j = 0; j < 4; ++j) {
            unsigned short h = f2bf_rne(r[j]);
            hp[j] = h;
            lp[j] = f2bf_rne(r[j] - bf2f(h));
        }
        ((ushort4*)xhi)[i] = hs;
        ((ushort4*)xlo)[i] = ls;
    }
}

// ---------------- propagation: gathers bf16(hi), accumulates fp32, writes hi/lo ----------------
__global__ void prop_kernel(const unsigned short* __restrict__ hsrc,
                            const int* __restrict__ offsets,
                            const int* __restrict__ csr_row, const float* __restrict__ csr_norm,
                            unsigned short* __restrict__ Ohi, unsigned short* __restrict__ Olo,
                            int n) {
    int node = blockIdx.x * 4 + (threadIdx.x >> 6);
    int lane = threadIdx.x & 63;
    if (node >= n) return;
    int beg = offsets[node], end = offsets[node + 1];
    float4 acc = make_float4(0.f, 0.f, 0.f, 0.f);
    int i = beg;
    for (; i + 2 <= end; i += 2) {
        int s0 = csr_row[i], s1 = csr_row[i + 1];
        float w0 = csr_norm[i], w1 = csr_norm[i + 1];
        ushort4 v0 = ((const ushort4*)(hsrc + (size_t)s0 * HID))[lane];
        ushort4 v1 = ((const ushort4*)(hsrc + (size_t)s1 * HID))[lane];
        acc.x += w0 * bf2f(v0.x); acc.y += w0 * bf2f(v0.y);
        acc.z += w0 * bf2f(v0.z); acc.w += w0 * bf2f(v0.w);
        acc.x += w1 * bf2f(v1.x); acc.y += w1 * bf2f(v1.y);
        acc.z += w1 * bf2f(v1.z); acc.w += w1 * bf2f(v1.w);
    }
    if (i < end) {
        int s0 = csr_row[i];
        float w0 = csr_norm[i];
        ushort4 v0 = ((const ushort4*)(hsrc + (size_t)s0 * HID))[lane];
        acc.x += w0 * bf2f(v0.x); acc.y += w0 * bf2f(v0.y);
        acc.z += w0 * bf2f(v0.z); acc.w += w0 * bf2f(v0.w);
    }
    float r[4] = {acc.x, acc.y, acc.z, acc.w};
    ushort4 hs, ls;
    unsigned short* hp = (unsigned short*)&hs;
    unsigned short* lp = (unsigned short*)&ls;
    #pragma unroll
    for (int j = 0; j < 4; ++j) {
        unsigned short h = f2bf_rne(r[j]);
        hp[j] = h;
        lp[j] = f2bf_rne(r[j] - bf2f(h));
    }
    ((ushort4*)(Ohi + (size_t)node * HID))[lane] = hs;
    ((ushort4*)(Olo + (size_t)node * HID))[lane] = ls;
}

// ---------------- tiled transpose + hi/lo split: src[R][C] -> dst[C][R] bf16 pair ----------------
__global__ void transpose_split_kernel(const float* __restrict__ src,
                                       unsigned short* __restrict__ dhi,
                                       unsigned short* __restrict__ dlo, int R, int C) {
    __shared__ float tile[32][33];
    int c0 = blockIdx.x * 32, r0 = blockIdx.y * 32;
    int tx = threadIdx.x, ty = threadIdx.y;   // block (32, 8)
    #pragma unroll
    for (int i = 0; i < 32; i += 8) {
        int r = r0 + ty + i, c = c0 + tx;
        tile[ty + i][tx] = (r < R && c < C) ? src[(size_t)r * C + c] : 0.f;
    }
    __syncthreads();
    #pragma unroll
    for (int i = 0; i < 32; i += 8) {
        int c = c0 + ty + i, r = r0 + tx;
        if (c < C && r < R) {
            float f = tile[tx][ty + i];
            unsigned short h = f2bf_rne(f);
            dhi[(size_t)c * R + r] = h;
            dlo[(size_t)c * R + r] = f2bf_rne(f - bf2f(h));
        }
    }
}

// ---------------- MFMA GEMM on pre-split bf16 hi/lo operands ----------------
// A rows padded to N_PAD (garbage pad rows discarded by epilogue mask).
// W rows (Kout dim) padded to multiple of 128.
#define GBM 128
#define GBN 128
#define GBK 32

template<int ACT, int OUTMODE>  // ACT: relu; OUTMODE: 0 = fp32 C, 1 = bf16 hi/lo pair
__global__ __launch_bounds__(256)
void mfma_gemm_kernel(const unsigned short* __restrict__ A0h, const unsigned short* __restrict__ A0l,
                      const unsigned short* __restrict__ A1h, const unsigned short* __restrict__ A1l,
                      const unsigned short* __restrict__ A2h, const unsigned short* __restrict__ A2l,
                      const unsigned short* __restrict__ Wh, const unsigned short* __restrict__ Wl,
                      const float* __restrict__ bvec,
                      float* __restrict__ C, unsigned short* __restrict__ Chi,
                      unsigned short* __restrict__ Clo,
                      int M, int K, int seg, int Kout) {
    // [kgroup(4)][row(128)][8 bf16] -> ds_read_b128 conflict-free
    __shared__ __attribute__((aligned(16))) unsigned short As_hi[4 * GBM * 8];
    __shared__ __attribute__((aligned(16))) unsigned short As_lo[4 * GBM * 8];
    __shared__ __attribute__((aligned(16))) unsigned short Bs_hi[4 * GBN * 8];
    __shared__ __attribute__((aligned(16))) unsigned short Bs_lo[4 * GBN * 8];

    int tid  = threadIdx.x;
    int lane = tid & 63;
    int w    = tid >> 6;                   // wave id; also the kgroup this wave stages
    int wm   = w & 1, wn = w >> 1;         // 2x2 waves, 64x64 each
    int kg   = lane >> 4, lr = lane & 15;  // fragment lane decomposition
    int bm = blockIdx.x * GBM, bn = blockIdx.y * GBN;

    f32x4 acc[4][4];
    #pragma unroll
    for (int i = 0; i < 4; ++i)
        #pragma unroll
        for (int j = 0; j < 4; ++j)
            acc[i][j] = (f32x4){0.f, 0.f, 0.f, 0.f};

    for (int k0 = 0; k0 < K; k0 += GBK) {
        const unsigned short *Aph, *Apl; int kl0;
        if (k0 < seg)          { Aph = A0h; Apl = A0l; kl0 = k0; }
        else if (k0 < 2 * seg) { Aph = A1h; Apl = A1l; kl0 = k0 - seg; }
        else                   { Aph = A2h; Apl = A2l; kl0 = k0 - 2 * seg; }

        __syncthreads();
        {
            const unsigned short* ah0 = Aph + (size_t)bm * seg + kl0 + w * 8;
            const unsigned short* al0 = Apl + (size_t)bm * seg + kl0 + w * 8;
            const unsigned short* bh0 = Wh + (size_t)bn * K + k0 + w * 8;
            const unsigned short* bl0 = Wl + (size_t)bn * K + k0 + w * 8;
            gload_lds16(ah0 + (size_t)lane * seg,        &As_hi[(w * 128) * 8]);
            gload_lds16(ah0 + (size_t)(lane + 64) * seg, &As_hi[(w * 128 + 64) * 8]);
            gload_lds16(al0 + (size_t)lane * seg,        &As_lo[(w * 128) * 8]);
            gload_lds16(al0 + (size_t)(lane + 64) * seg, &As_lo[(w * 128 + 64) * 8]);
            gload_lds16(bh0 + (size_t)lane * K,          &Bs_hi[(w * 128) * 8]);
            gload_lds16(bh0 + (size_t)(lane + 64) * K,   &Bs_hi[(w * 128 + 64) * 8]);
            gload_lds16(bl0 + (size_t)lane * K,          &Bs_lo[(w * 128) * 8]);
            gload_lds16(bl0 + (size_t)(lane + 64) * K,   &Bs_lo[(w * 128 + 64) * 8]);
        }
        __syncthreads();

        // ---- fragments + MFMA ----
        s16x8 ah[4], al[4], bh[4], bl[4];
        int abase = (kg * GBM + wm * 64 + lr) * 8;
        int bbase = (kg * GBN + wn * 64 + lr) * 8;
        #pragma unroll
        for (int mf = 0; mf < 4; ++mf) {
            ah[mf] = *(const s16x8*)&As_hi[abase + mf * 16 * 8];
            al[mf] = *(const s16x8*)&As_lo[abase + mf * 16 * 8];
        }
        #pragma unroll
        for (int nf = 0; nf < 4; ++nf) {
            bh[nf] = *(const s16x8*)&Bs_hi[bbase + nf * 16 * 8];
            bl[nf] = *(const s16x8*)&Bs_lo[bbase + nf * 16 * 8];
        }
        #pragma unroll
        for (int mf = 0; mf < 4; ++mf)
            #pragma unroll
            for (int nf = 0; nf < 4; ++nf) {
                acc[mf][nf] = __builtin_amdgcn_mfma_f32_16x16x32_bf16(ah[mf], bh[nf], acc[mf][nf], 0, 0, 0);
                acc[mf][nf] = __builtin_amdgcn_mfma_f32_16x16x32_bf16(al[mf], bh[nf], acc[mf][nf], 0, 0, 0);
                acc[mf][nf] = __builtin_amdgcn_mfma_f32_16x16x32_bf16(ah[mf], bl[nf], acc[mf][nf], 0, 0, 0);
            }
    }

    // ---- epilogue: C/D layout col = lane&15, row = (lane>>4)*4 + reg ----
    #pragma unroll
    for (int nf = 0; nf < 4; ++nf) {
        int col = bn + wn * 64 + nf * 16 + lr;
        if (col >= Kout) continue;
        float bv = bvec[col];
        #pragma unroll
        for (int mf = 0; mf < 4; ++mf) {
            #pragma unroll
            for (int i = 0; i < 4; ++i) {
                int rw = bm + wm * 64 + mf * 16 + kg * 4 + i;
                if (rw < M) {
                    float v = acc[mf][nf][i] + bv;
                    if (ACT == 1) v = fmaxf(v, 0.f);
                    if (OUTMODE == 0) {
                        C[(size_t)rw * Kout + col] = v;
                    } else {
                        unsigned short hs = f2bf_rne(v);
                        Chi[(size_t)rw * Kout + col] = hs;
                        Clo[(size_t)rw * Kout + col] = f2bf_rne(v - bf2f(hs));
                    }
                }
            }
        }
    }
}

// ---------------- BN column stats ----------------
__global__ void colstats_kernel(const float* __restrict__ y, float* __restrict__ sums,
                                float* __restrict__ sumsq, int M) {
    int col = threadIdx.x;  // 256 threads = HID
    int r0 = blockIdx.x * 128;
    int r1 = min(r0 + 128, M);
    float s = 0.f, s2 = 0.f;
    for (int r = r0; r < r1; ++r) {
        float v = y[(size_t)r * HID + col];
        s += v; s2 += v * v;
    }
    atomicAdd(&sums[col], s);
    atomicAdd(&sumsq[col], s2);
}

__global__ void bnrelu_kernel(const float* __restrict__ y, const float* __restrict__ sums,
                              const float* __restrict__ sumsq, const float* __restrict__ g,
                              const float* __restrict__ beta,
                              unsigned short* __restrict__ Hhi, unsigned short* __restrict__ Hlo,
                              int M) {
    int idx = blockIdx.x * blockDim.x + threadIdx.x;   // group of 4 channels
    if (idx < M * HID / 4) {
        int col0 = (idx * 4) & (HID - 1);
        float4 v = ((const float4*)y)[idx];
        float invM = 1.0f / (float)M;
        float r[4] = {v.x, v.y, v.z, v.w};
        ushort4 hs, ls;
        unsigned short* hp = (unsigned short*)&hs;
        unsigned short* lp = (unsigned short*)&ls;
        #pragma unroll
        for (int j = 0; j < 4; ++j) {
            int col = col0 + j;
            float mean = sums[col] * invM;
            float var  = fmaxf(sumsq[col] * invM - mean * mean, 0.f);
            float o = (r[j] - mean) * rsqrtf(var + BN_EPS) * g[col] + beta[col];
            o = fmaxf(o, 0.f);
            unsigned short h = f2bf_rne(o);
            hp[j] = h;
            lp[j] = f2bf_rne(o - bf2f(h));
        }
        ((ushort4*)Hhi)[idx] = hs;
        ((ushort4*)Hlo)[idx] = ls;
    }
}

extern "C" void kernel_launch(void* const* d_in, const int* in_sizes, int n_in,
                              void* d_out, int out_size, void* d_ws, size_t ws_size,
                              hipStream_t stream) {
    const float* x      = (const float*)d_in[0];
    const int*   ei     = (const int*)d_in[1];
    const float* W_feat = (const float*)d_in[2];
    const float* b_feat = (const float*)d_in[3];
    const float* W0     = (const float*)d_in[4];
    const float* b0     = (const float*)d_in[5];
    const float* g0     = (const float*)d_in[6];
    const float* beta0  = (const float*)d_in[7];
    const float* W1     = (const float*)d_in[8];
    const float* b1     = (const float*)d_in[9];
    const float* g1     = (const float*)d_in[10];
    const float* beta1  = (const float*)d_in[11];
    const float* Wc     = (const float*)d_in[12];
    const float* bc     = (const float*)d_in[13];
    float* out = (float*)d_out;

    const int N = N_NODES, E = N_EDGES;
    const int* row = ei;
    const int* col = ei + E;

    // workspace carve-up
    char* ws = (char*)d_ws;
    size_t off = 0;
    auto alloc = [&](size_t bytes) -> void* {
        void* p = ws + off;
        off = (off + bytes + 255) & ~(size_t)255;
        return p;
    };
    int*   deg_row  = (int*)  alloc(N * 4);
    int*   deg_col  = (int*)  alloc(N * 4);
    int*   cursor   = (int*)  alloc(N * 4);
    int*   offsets  = (int*)  alloc((N + 1) * 4);
    float* dis      = (float*)alloc(N * 4);
    int*   csr_row  = (int*)  alloc((size_t)E * 4);
    float* csr_norm = (float*)alloc((size_t)E * 4);
    unsigned short* x_hi    = (unsigned short*)alloc((size_t)N_PAD * IN_CH * 2);
    unsigned short* x_lo    = (unsigned short*)alloc((size_t)N_PAD * IN_CH * 2);
    unsigned short* h_hi    = (unsigned short*)alloc((size_t)N_PAD * HID * 2);
    unsigned short* h_lo    = (unsigned short*)alloc((size_t)N_PAD * HID * 2);
    unsigned short* agg1_hi = (unsigned short*)alloc((size_t)N_PAD * HID * 2);
    unsigned short* agg1_lo = (unsigned short*)alloc((size_t)N_PAD * HID * 2);
    // lifetime aliasing: x_hi/x_lo are dead after the feat GEMM; reuse the region
    unsigned short* agg2_hi = x_hi;                                   // 25.6 MB
    unsigned short* agg2_lo = x_hi + (size_t)N_PAD * HID;             // 25.6 MB (still in x_hi block)
    float*          y       = (float*)x_lo;                          // 51.2 MB
    float* sums     = (float*)alloc(HID * 4);
    float* sumsq    = (float*)alloc(HID * 4);
    unsigned short* WTf_hi = (unsigned short*)alloc((size_t)HID * IN_CH * 2);
    unsigned short* WTf_lo = (unsigned short*)alloc((size_t)HID * IN_CH * 2);
    unsigned short* WT0_hi = (unsigned short*)alloc((size_t)HID * 3 * HID * 2);
    unsigned short* WT0_lo = (unsigned short*)alloc((size_t)HID * 3 * HID * 2);
    unsigned short* WT1_hi = (unsigned short*)alloc((size_t)HID * 3 * HID * 2);
    unsigned short* WT1_lo = (unsigned short*)alloc((size_t)HID * 3 * HID * 2);
    unsigned short* WTc_hi = (unsigned short*)alloc((size_t)128 * HID * 2);   // 40 rows padded to 128
    unsigned short* WTc_lo = (unsigned short*)alloc((size_t)128 * HID * 2);

    hipMemsetAsync(deg_row, 0, N * 4, stream);
    hipMemsetAsync(deg_col, 0, N * 4, stream);
    hipMemsetAsync(cursor, 0, N * 4, stream);

    // operand pre-splits (independent of CSR build)
    split_x_kernel<<<(N * IN_CH / 4 + 255) / 256, 256, 0, stream>>>(x, x_hi, x_lo, N * IN_CH / 4);
    dim3 tb(32, 8);
    transpose_split_kernel<<<dim3(HID / 32, IN_CH / 32), tb, 0, stream>>>(W_feat, WTf_hi, WTf_lo, IN_CH, HID);
    transpose_split_kernel<<<dim3(HID / 32, 3 * HID / 32), tb, 0, stream>>>(W0, WT0_hi, WT0_lo, 3 * HID, HID);
    transpose_split_kernel<<<dim3(HID / 32, 3 * HID / 32), tb, 0, stream>>>(W1, WT1_hi, WT1_lo, 3 * HID, HID);
    transpose_split_kernel<<<dim3((OUT_CH + 31) / 32, HID / 32), tb, 0, stream>>>(Wc, WTc_hi, WTc_lo, HID, OUT_CH);

    count_deg_kernel<<<(E + 255) / 256, 256, 0, stream>>>(row, col, deg_row, deg_col, E);
    dis_kernel<<<(N + 255) / 256, 256, 0, stream>>>(deg_row, dis, N);
    scan_kernel<<<1, 1024, 0, stream>>>(deg_col, offsets, N);
    fill_csr_kernel<<<(E + 255) / 256, 256, 0, stream>>>(row, col, dis, offsets, cursor,
                                                         csr_row, csr_norm, E);

    dim3 gemm_grid((N + GBM - 1) / GBM, HID / GBN);
    // h = relu(x @ W_feat + b_feat) -> hi/lo pair
    mfma_gemm_kernel<1, 1><<<gemm_grid, 256, 0, stream>>>(
        x_hi, x_lo, nullptr, nullptr, nullptr, nullptr, WTf_hi, WTf_lo, b_feat,
        nullptr, h_hi, h_lo, N, IN_CH, IN_CH, HID);

    const unsigned short* WThs[2] = {WT0_hi, WT1_hi};
    const unsigned short* WTls[2] = {WT0_lo, WT1_lo};
    const float* bs[2]    = {b0, b1};
    const float* gs[2]    = {g0, g1};
    const float* betas[2] = {beta0, beta1};
    int prop_grid = (N + 3) / 4;
    for (int layer = 0; layer < 2; ++layer) {
        prop_kernel<<<prop_grid, 256, 0, stream>>>(h_hi, offsets, csr_row, csr_norm,
                                                   agg1_hi, agg1_lo, N);
        prop_kernel<<<prop_grid, 256, 0, stream>>>(agg1_hi, offsets, csr_row, csr_norm,
                                                   agg2_hi, agg2_lo, N);
        mfma_gemm_kernel<0, 0><<<gemm_grid, 256, 0, stream>>>(
            h_hi, h_lo, agg1_hi, agg1_lo, agg2_hi, agg2_lo, WThs[layer], WTls[layer], bs[layer],
            y, nullptr, nullptr, N, 3 * HID, HID, HID);
        hipMemsetAsync(sums, 0, HID * 4, stream);
        hipMemsetAsync(sumsq, 0, HID * 4, stream);
        colstats_kernel<<<(N + 127) / 128, HID, 0, stream>>>(y, sums, sumsq, N);
        bnrelu_kernel<<<(N * HID / 4 + 255) / 256, 256, 0, stream>>>(y, sums, sumsq, gs[layer],
                                                                     betas[layer], h_hi, h_lo, N);
    }

    dim3 out_grid((N + GBM - 1) / GBM, 1);
    mfma_gemm_kernel<0, 0><<<out_grid, 256, 0, stream>>>(
        h_hi, h_lo, nullptr, nullptr, nullptr, nullptr, WTc_hi, WTc_lo, bc,
        out, nullptr, nullptr, N, HID, HID, OUT_CH);
}

// Round 4
// 1257.138 us; speedup vs baseline: 1.9381x; 1.0520x over previous
//
#include <hip/hip_runtime.h>

#define N_NODES 50000
#define N_PAD   50176            // 392 * 128
#define N_EDGES 1600000
#define IN_CH   512
#define HID     256
#define OUT_CH  40
#define BN_EPS  1e-5f

typedef __attribute__((ext_vector_type(8))) short s16x8;
typedef __attribute__((ext_vector_type(8))) unsigned short u16x8;
typedef __attribute__((ext_vector_type(4))) float f32x4;

__device__ __forceinline__ unsigned short f2bf_rne(float f) {
    unsigned u = __float_as_uint(f);
    u += 0x7FFFu + ((u >> 16) & 1u);
    return (unsigned short)(u >> 16);
}
__device__ __forceinline__ float bf2f(unsigned short s) {
    return __uint_as_float((unsigned)s << 16);
}

// async global->LDS, 16B per lane; LDS dest is wave-uniform base + lane*16
__device__ __forceinline__ void gload_lds16(const void* gsrc, void* ldst) {
    __builtin_amdgcn_global_load_lds(
        (const __attribute__((address_space(1))) unsigned int*)gsrc,
        (__attribute__((address_space(3))) unsigned int*)ldst,
        16, 0, 0);
}

// ---------------- degree counting ----------------
__global__ void count_deg_kernel(const int* __restrict__ row, const int* __restrict__ col,
                                 int* __restrict__ deg_row, int* __restrict__ deg_col, int E) {
    int e = blockIdx.x * blockDim.x + threadIdx.x;
    if (e < E) {
        atomicAdd(&deg_row[row[e]], 1);
        atomicAdd(&deg_col[col[e]], 1);
    }
}

__global__ void dis_kernel(const int* __restrict__ deg_row, float* __restrict__ dis, int n) {
    int i = blockIdx.x * blockDim.x + threadIdx.x;
    if (i < n) {
        float d = (float)max(deg_row[i], 1);
        dis[i] = rsqrtf(d);
    }
}

// ---------------- exclusive prefix sum (single block) ----------------
__global__ void scan_kernel(const int* __restrict__ deg, int* __restrict__ offsets, int n) {
    __shared__ int tmp[1024];
    __shared__ int carry_s;
    int tid = threadIdx.x;
    if (tid == 0) { carry_s = 0; offsets[0] = 0; }
    __syncthreads();
    for (int base = 0; base < n; base += 1024) {
        int v = (base + tid < n) ? deg[base + tid] : 0;
        tmp[tid] = v;
        __syncthreads();
        for (int off = 1; off < 1024; off <<= 1) {
            int t = (tid >= off) ? tmp[tid - off] : 0;
            __syncthreads();
            tmp[tid] += t;
            __syncthreads();
        }
        if (base + tid < n) offsets[base + tid + 1] = carry_s + tmp[tid];
        __syncthreads();
        if (tid == 0) carry_s += tmp[1023];
        __syncthreads();
    }
}

// ---------------- CSR fill (group edges by destination col) ----------------
__global__ void fill_csr_kernel(const int* __restrict__ row, const int* __restrict__ col,
                                const float* __restrict__ dis, const int* __restrict__ offsets,
                                int* __restrict__ cursor, int* __restrict__ csr_row,
                                float* __restrict__ csr_norm, int E) {
    int e = blockIdx.x * blockDim.x + threadIdx.x;
    if (e < E) {
        int r = row[e], c = col[e];
        int pos = atomicAdd(&cursor[c], 1);
        int idx = offsets[c] + pos;
        csr_row[idx] = r;
        csr_norm[idx] = dis[r] * dis[c];
    }
}

// ---------------- x hi/lo split ----------------
__global__ void split_x_kernel(const float* __restrict__ x, unsigned short* __restrict__ xhi,
                               unsigned short* __restrict__ xlo, int n4) {
    int i = blockIdx.x * blockDim.x + threadIdx.x;
    if (i < n4) {
        float4 v = ((const float4*)x)[i];
        float r[4] = {v.x, v.y, v.z, v.w};
        ushort4 hs, ls;
        unsigned short* hp = (unsigned short*)&hs;
        unsigned short* lp = (unsigned short*)&ls;
        #pragma unroll
        for (int j = 0; j < 4; ++j) {
            unsigned short h = f2bf_rne(r[j]);
            hp[j] = h;
            lp[j] = f2bf_rne(r[j] - bf2f(h));
        }
        ((ushort4*)xhi)[i] = hs;
        ((ushort4*)xlo)[i] = ls;
    }
}

// ---------------- propagation ----------------
// 1 node per wave; 2 half-waves process 2 edges/iter (x2 unroll -> 4 edges in flight);
// 16B gathers; cross-half shfl_xor reduce; half0 writes hi, half1 writes lo.
__global__ void prop_kernel(const unsigned short* __restrict__ hsrc,
                            const int* __restrict__ offsets,
                            const int* __restrict__ csr_row, const float* __restrict__ csr_norm,
                            unsigned short* __restrict__ Ohi, unsigned short* __restrict__ Olo,
                            int n) {
    int node = blockIdx.x * 4 + (threadIdx.x >> 6);
    if (node >= n) return;
    int lane = threadIdx.x & 63;
    int half = lane >> 5;
    int cl   = lane & 31;           // 16B chunk id within the 512B row
    int beg = offsets[node], end = offsets[node + 1];
    float acc[8] = {0.f, 0.f, 0.f, 0.f, 0.f, 0.f, 0.f, 0.f};
    for (int i = beg; i < end; i += 4) {
        int i0 = i + half;
        int i1 = i + 2 + half;
        int e0 = min(i0, end - 1), e1 = min(i1, end - 1);
        float w0 = (i0 < end) ? csr_norm[i0] : 0.f;
        float w1 = (i1 < end) ? csr_norm[i1] : 0.f;
        int s0 = csr_row[e0], s1 = csr_row[e1];
        u16x8 v0 = *(const u16x8*)(hsrc + (size_t)s0 * HID + cl * 8);
        u16x8 v1 = *(const u16x8*)(hsrc + (size_t)s1 * HID + cl * 8);
        #pragma unroll
        for (int j = 0; j < 8; ++j)
            acc[j] += w0 * bf2f((unsigned short)v0[j]) + w1 * bf2f((unsigned short)v1[j]);
    }
    #pragma unroll
    for (int j = 0; j < 8; ++j) acc[j] += __shfl_xor(acc[j], 32);
    u16x8 ov;
    if (half == 0) {
        #pragma unroll
        for (int j = 0; j < 8; ++j) ov[j] = f2bf_rne(acc[j]);
        *(u16x8*)(Ohi + (size_t)node * HID + cl * 8) = ov;
    } else {
        #pragma unroll
        for (int j = 0; j < 8; ++j) {
            unsigned short h = f2bf_rne(acc[j]);
            ov[j] = f2bf_rne(acc[j] - bf2f(h));
        }
        *(u16x8*)(Olo + (size_t)node * HID + cl * 8) = ov;
    }
}

// ---------------- tiled transpose + hi/lo split: src[R][C] -> dst[C][R] bf16 pair ----------------
__global__ void transpose_split_kernel(const float* __restrict__ src,
                                       unsigned short* __restrict__ dhi,
                                       unsigned short* __restrict__ dlo, int R, int C) {
    __shared__ float tile[32][33];
    int c0 = blockIdx.x * 32, r0 = blockIdx.y * 32;
    int tx = threadIdx.x, ty = threadIdx.y;   // block (32, 8)
    #pragma unroll
    for (int i = 0; i < 32; i += 8) {
        int r = r0 + ty + i, c = c0 + tx;
        tile[ty + i][tx] = (r < R && c < C) ? src[(size_t)r * C + c] : 0.f;
    }
    __syncthreads();
    #pragma unroll
    for (int i = 0; i < 32; i += 8) {
        int c = c0 + ty + i, r = r0 + tx;
        if (c < C && r < R) {
            float f = tile[tx][ty + i];
            unsigned short h = f2bf_rne(f);
            dhi[(size_t)c * R + r] = h;
            dlo[(size_t)c * R + r] = f2bf_rne(f - bf2f(h));
        }
    }
}

// ---------------- MFMA GEMM, double-buffered LDS, counted-overlap 2-phase ----------------
#define GBM 128
#define GBN 128
#define GBK 32

template<int ACT, int OUTMODE, int NC>   // NC = number of column blocks (2 -> XCD-paired swizzle)
__global__ __launch_bounds__(256)
void mfma_gemm_kernel(const unsigned short* __restrict__ A0h, const unsigned short* __restrict__ A0l,
                      const unsigned short* __restrict__ A1h, const unsigned short* __restrict__ A1l,
                      const unsigned short* __restrict__ A2h, const unsigned short* __restrict__ A2l,
                      const unsigned short* __restrict__ Wh, const unsigned short* __restrict__ Wl,
                      const float* __restrict__ bvec,
                      float* __restrict__ C, unsigned short* __restrict__ Chi,
                      unsigned short* __restrict__ Clo,
                      int M, int K, int seg, int Kout) {
    // [buf][kgroup(4)][row(128)][8 bf16]; 8KB per plane per buf -> 64KB total
    __shared__ __attribute__((aligned(16))) unsigned short As_hi[2][4 * GBM * 8];
    __shared__ __attribute__((aligned(16))) unsigned short As_lo[2][4 * GBM * 8];
    __shared__ __attribute__((aligned(16))) unsigned short Bs_hi[2][4 * GBN * 8];
    __shared__ __attribute__((aligned(16))) unsigned short Bs_lo[2][4 * GBN * 8];

    int tid  = threadIdx.x;
    int lane = tid & 63;
    int w    = tid >> 6;                   // wave id == the kgroup this wave stages
    int wm   = w & 1, wn = w >> 1;         // 2x2 waves, 64x64 each
    int kg   = lane >> 4, lr = lane & 15;

    int bid = blockIdx.x, p, c;
    if (NC == 2) { p = ((bid >> 4) << 3) + (bid & 7); c = (bid >> 3) & 1; }
    else         { p = bid; c = 0; }
    int bm = p * GBM, bn = c * GBN;

    f32x4 acc[4][4];
    #pragma unroll
    for (int i = 0; i < 4; ++i)
        #pragma unroll
        for (int j = 0; j < 4; ++j)
            acc[i][j] = (f32x4){0.f, 0.f, 0.f, 0.f};

    auto STAGE = [&](int buf, int k0) {
        const unsigned short *Aph, *Apl; int kl0;
        if (k0 < seg)          { Aph = A0h; Apl = A0l; kl0 = k0; }
        else if (k0 < 2 * seg) { Aph = A1h; Apl = A1l; kl0 = k0 - seg; }
        else                   { Aph = A2h; Apl = A2l; kl0 = k0 - 2 * seg; }
        const unsigned short* a_h = Aph + (size_t)(bm + lane) * seg + kl0 + w * 8;
        const unsigned short* a_l = Apl + (size_t)(bm + lane) * seg + kl0 + w * 8;
        const unsigned short* b_h = Wh + (size_t)(bn + lane) * K + k0 + w * 8;
        const unsigned short* b_l = Wl + (size_t)(bn + lane) * K + k0 + w * 8;
        size_t rA = (size_t)64 * seg, rB = (size_t)64 * K;
        gload_lds16(a_h,      &As_hi[buf][(w * 128) * 8]);
        gload_lds16(a_h + rA, &As_hi[buf][(w * 128 + 64) * 8]);
        gload_lds16(a_l,      &As_lo[buf][(w * 128) * 8]);
        gload_lds16(a_l + rA, &As_lo[buf][(w * 128 + 64) * 8]);
        gload_lds16(b_h,      &Bs_hi[buf][(w * 128) * 8]);
        gload_lds16(b_h + rB, &Bs_hi[buf][(w * 128 + 64) * 8]);
        gload_lds16(b_l,      &Bs_lo[buf][(w * 128) * 8]);
        gload_lds16(b_l + rB, &Bs_lo[buf][(w * 128 + 64) * 8]);
    };

    int nt = K / GBK;
    STAGE(0, 0);
    asm volatile("s_waitcnt vmcnt(0)" ::: "memory");
    __builtin_amdgcn_s_barrier();
    __builtin_amdgcn_sched_barrier(0);

    for (int t = 0; t < nt; ++t) {
        int cur = t & 1;
        if (t + 1 < nt) STAGE(cur ^ 1, (t + 1) * GBK);   // overlaps this step's compute

        int abase = (kg * GBM + wm * 64 + lr) * 8;
        int bbase = (kg * GBN + wn * 64 + lr) * 8;
        s16x8 ah[4], al[4], bh[4], bl[4];
        #pragma unroll
        for (int mf = 0; mf < 4; ++mf) {
            ah[mf] = *(const s16x8*)&As_hi[cur][abase + mf * 16 * 8];
            al[mf] = *(const s16x8*)&As_lo[cur][abase + mf * 16 * 8];
        }
        #pragma unroll
        for (int nf = 0; nf < 4; ++nf) {
            bh[nf] = *(const s16x8*)&Bs_hi[cur][bbase + nf * 16 * 8];
            bl[nf] = *(const s16x8*)&Bs_lo[cur][bbase + nf * 16 * 8];
        }
        #pragma unroll
        for (int mf = 0; mf < 4; ++mf)
            #pragma unroll
            for (int nf = 0; nf < 4; ++nf) {
                acc[mf][nf] = __builtin_amdgcn_mfma_f32_16x16x32_bf16(ah[mf], bh[nf], acc[mf][nf], 0, 0, 0);
                acc[mf][nf] = __builtin_amdgcn_mfma_f32_16x16x32_bf16(al[mf], bh[nf], acc[mf][nf], 0, 0, 0);
                acc[mf][nf] = __builtin_amdgcn_mfma_f32_16x16x32_bf16(ah[mf], bl[nf], acc[mf][nf], 0, 0, 0);
            }

        asm volatile("s_waitcnt vmcnt(0)" ::: "memory");  // next tile landed
        __builtin_amdgcn_s_barrier();                     // all reads of buf 'cur' done
        __builtin_amdgcn_sched_barrier(0);
    }

    // ---- epilogue: C/D layout col = lane&15, row = (lane>>4)*4 + reg ----
    #pragma unroll
    for (int nf = 0; nf < 4; ++nf) {
        int col = bn + wn * 64 + nf * 16 + lr;
        if (col >= Kout) continue;
        float bv = bvec[col];
        #pragma unroll
        for (int mf = 0; mf < 4; ++mf) {
            #pragma unroll
            for (int i = 0; i < 4; ++i) {
                int rw = bm + wm * 64 + mf * 16 + kg * 4 + i;
                if (rw < M) {
                    float v = acc[mf][nf][i] + bv;
                    if (ACT == 1) v = fmaxf(v, 0.f);
                    if (OUTMODE == 0) {
                        C[(size_t)rw * Kout + col] = v;
                    } else {
                        unsigned short hs = f2bf_rne(v);
                        Chi[(size_t)rw * Kout + col] = hs;
                        Clo[(size_t)rw * Kout + col] = f2bf_rne(v - bf2f(hs));
                    }
                }
            }
        }
    }
}

// ---------------- BN column stats ----------------
__global__ void colstats_kernel(const float* __restrict__ y, float* __restrict__ sums,
                                float* __restrict__ sumsq, int M) {
    int col = threadIdx.x;  // 256 threads = HID
    int r0 = blockIdx.x * 128;
    int r1 = min(r0 + 128, M);
    float s = 0.f, s2 = 0.f;
    for (int r = r0; r < r1; ++r) {
        float v = y[(size_t)r * HID + col];
        s += v; s2 += v * v;
    }
    atomicAdd(&sums[col], s);
    atomicAdd(&sumsq[col], s2);
}

__global__ void bnrelu_kernel(const float* __restrict__ y, const float* __restrict__ sums,
                              const float* __restrict__ sumsq, const float* __restrict__ g,
                              const float* __restrict__ beta,
                              unsigned short* __restrict__ Hhi, unsigned short* __restrict__ Hlo,
                              int M) {
    int idx = blockIdx.x * blockDim.x + threadIdx.x;   // group of 4 channels
    if (idx < M * HID / 4) {
        int col0 = (idx * 4) & (HID - 1);
        float4 v = ((const float4*)y)[idx];
        float invM = 1.0f / (float)M;
        float r[4] = {v.x, v.y, v.z, v.w};
        ushort4 hs, ls;
        unsigned short* hp = (unsigned short*)&hs;
        unsigned short* lp = (unsigned short*)&ls;
        #pragma unroll
        for (int j = 0; j < 4; ++j) {
            int col = col0 + j;
            float mean = sums[col] * invM;
            float var  = fmaxf(sumsq[col] * invM - mean * mean, 0.f);
            float o = (r[j] - mean) * rsqrtf(var + BN_EPS) * g[col] + beta[col];
            o = fmaxf(o, 0.f);
            unsigned short h = f2bf_rne(o);
            hp[j] = h;
            lp[j] = f2bf_rne(o - bf2f(h));
        }
        ((ushort4*)Hhi)[idx] = hs;
        ((ushort4*)Hlo)[idx] = ls;
    }
}

extern "C" void kernel_launch(void* const* d_in, const int* in_sizes, int n_in,
                              void* d_out, int out_size, void* d_ws, size_t ws_size,
                              hipStream_t stream) {
    const float* x      = (const float*)d_in[0];
    const int*   ei     = (const int*)d_in[1];
    const float* W_feat = (const float*)d_in[2];
    const float* b_feat = (const float*)d_in[3];
    const float* W0     = (const float*)d_in[4];
    const float* b0     = (const float*)d_in[5];
    const float* g0     = (const float*)d_in[6];
    const float* beta0  = (const float*)d_in[7];
    const float* W1     = (const float*)d_in[8];
    const float* b1     = (const float*)d_in[9];
    const float* g1     = (const float*)d_in[10];
    const float* beta1  = (const float*)d_in[11];
    const float* Wc     = (const float*)d_in[12];
    const float* bc     = (const float*)d_in[13];
    float* out = (float*)d_out;

    const int N = N_NODES, E = N_EDGES;
    const int* row = ei;
    const int* col = ei + E;

    // workspace carve-up
    char* ws = (char*)d_ws;
    size_t off = 0;
    auto alloc = [&](size_t bytes) -> void* {
        void* p = ws + off;
        off = (off + bytes + 255) & ~(size_t)255;
        return p;
    };
    int*   deg_row  = (int*)  alloc(N * 4);
    int*   deg_col  = (int*)  alloc(N * 4);
    int*   cursor   = (int*)  alloc(N * 4);
    int*   offsets  = (int*)  alloc((N + 1) * 4);
    float* dis      = (float*)alloc(N * 4);
    int*   csr_row  = (int*)  alloc((size_t)E * 4);
    float* csr_norm = (float*)alloc((size_t)E * 4);
    unsigned short* x_hi    = (unsigned short*)alloc((size_t)N_PAD * IN_CH * 2);
    unsigned short* x_lo    = (unsigned short*)alloc((size_t)N_PAD * IN_CH * 2);
    unsigned short* h_hi    = (unsigned short*)alloc((size_t)N_PAD * HID * 2);
    unsigned short* h_lo    = (unsigned short*)alloc((size_t)N_PAD * HID * 2);
    unsigned short* agg1_hi = (unsigned short*)alloc((size_t)N_PAD * HID * 2);
    unsigned short* agg1_lo = (unsigned short*)alloc((size_t)N_PAD * HID * 2);
    // lifetime aliasing: x_hi/x_lo are dead after the feat GEMM; reuse the region
    unsigned short* agg2_hi = x_hi;
    unsigned short* agg2_lo = x_hi + (size_t)N_PAD * HID;
    float*          y       = (float*)x_lo;
    float* sums     = (float*)alloc(HID * 4);
    float* sumsq    = (float*)alloc(HID * 4);
    unsigned short* WTf_hi = (unsigned short*)alloc((size_t)HID * IN_CH * 2);
    unsigned short* WTf_lo = (unsigned short*)alloc((size_t)HID * IN_CH * 2);
    unsigned short* WT0_hi = (unsigned short*)alloc((size_t)HID * 3 * HID * 2);
    unsigned short* WT0_lo = (unsigned short*)alloc((size_t)HID * 3 * HID * 2);
    unsigned short* WT1_hi = (unsigned short*)alloc((size_t)HID * 3 * HID * 2);
    unsigned short* WT1_lo = (unsigned short*)alloc((size_t)HID * 3 * HID * 2);
    unsigned short* WTc_hi = (unsigned short*)alloc((size_t)128 * HID * 2);   // 40 rows padded to 128
    unsigned short* WTc_lo = (unsigned short*)alloc((size_t)128 * HID * 2);

    hipMemsetAsync(deg_row, 0, N * 4, stream);
    hipMemsetAsync(deg_col, 0, N * 4, stream);
    hipMemsetAsync(cursor, 0, N * 4, stream);
    hipMemsetAsync(WTc_hi, 0, (size_t)128 * HID * 2, stream);
    hipMemsetAsync(WTc_lo, 0, (size_t)128 * HID * 2, stream);

    // operand pre-splits (independent of CSR build)
    split_x_kernel<<<(N * IN_CH / 4 + 255) / 256, 256, 0, stream>>>(x, x_hi, x_lo, N * IN_CH / 4);
    dim3 tb(32, 8);
    transpose_split_kernel<<<dim3(HID / 32, IN_CH / 32), tb, 0, stream>>>(W_feat, WTf_hi, WTf_lo, IN_CH, HID);
    transpose_split_kernel<<<dim3(HID / 32, 3 * HID / 32), tb, 0, stream>>>(W0, WT0_hi, WT0_lo, 3 * HID, HID);
    transpose_split_kernel<<<dim3(HID / 32, 3 * HID / 32), tb, 0, stream>>>(W1, WT1_hi, WT1_lo, 3 * HID, HID);
    transpose_split_kernel<<<dim3((OUT_CH + 31) / 32, HID / 32), tb, 0, stream>>>(Wc, WTc_hi, WTc_lo, HID, OUT_CH);

    count_deg_kernel<<<(E + 255) / 256, 256, 0, stream>>>(row, col, deg_row, deg_col, E);
    dis_kernel<<<(N + 255) / 256, 256, 0, stream>>>(deg_row, dis, N);
    scan_kernel<<<1, 1024, 0, stream>>>(deg_col, offsets, N);
    fill_csr_kernel<<<(E + 255) / 256, 256, 0, stream>>>(row, col, dis, offsets, cursor,
                                                         csr_row, csr_norm, E);

    const int NPAN = N_PAD / GBM;          // 392 row-panels
    // h = relu(x @ W_feat + b_feat) -> hi/lo pair
    mfma_gemm_kernel<1, 1, 2><<<NPAN * 2, 256, 0, stream>>>(
        x_hi, x_lo, nullptr, nullptr, nullptr, nullptr, WTf_hi, WTf_lo, b_feat,
        nullptr, h_hi, h_lo, N, IN_CH, IN_CH, HID);

    const unsigned short* WThs[2] = {WT0_hi, WT1_hi};
    const unsigned short* WTls[2] = {WT0_lo, WT1_lo};
    const float* bs[2]    = {b0, b1};
    const float* gs[2]    = {g0, g1};
    const float* betas[2] = {beta0, beta1};
    int prop_grid = (N + 3) / 4;
    for (int layer = 0; layer < 2; ++layer) {
        prop_kernel<<<prop_grid, 256, 0, stream>>>(h_hi, offsets, csr_row, csr_norm,
                                                   agg1_hi, agg1_lo, N);
        prop_kernel<<<prop_grid, 256, 0, stream>>>(agg1_hi, offsets, csr_row, csr_norm,
                                                   agg2_hi, agg2_lo, N);
        mfma_gemm_kernel<0, 0, 2><<<NPAN * 2, 256, 0, stream>>>(
            h_hi, h_lo, agg1_hi, agg1_lo, agg2_hi, agg2_lo, WThs[layer], WTls[layer], bs[layer],
            y, nullptr, nullptr, N, 3 * HID, HID, HID);
        hipMemsetAsync(sums, 0, HID * 4, stream);
        hipMemsetAsync(sumsq, 0, HID * 4, stream);
        colstats_kernel<<<(N + 127) / 128, HID, 0, stream>>>(y, sums, sumsq, N);
        bnrelu_kernel<<<(N * HID / 4 + 255) / 256, 256, 0, stream>>>(y, sums, sumsq, gs[layer],
                                                                     betas[layer], h_hi, h_lo, N);
    }

    mfma_gemm_kernel<0, 0, 1><<<NPAN, 256, 0, stream>>>(
        h_hi, h_lo, nullptr, nullptr, nullptr, nullptr, WTc_hi, WTc_lo, bc,
        out, nullptr, nullptr, N, HID, HID, OUT_CH);
}